// Round 10
// baseline (555.361 us; speedup 1.0000x reference)
//
#include <hip/hip_runtime.h>
#include <cstdint>

typedef unsigned long long u64;
typedef unsigned int u32;

#define B_      32
#define CIN_    3
#define NPTS    4096
#define DIM_    256
#define PIECES_ 20

// ---------------------------------------------------------------------------
// Kernel 1: h = W2 @ relu(W1 @ x + b1) + b2, modeling modern np.einsum
// (FMA axpy, contraction index ascending, one accumulator, bias added last).
// Verified bit-exact vs the np reference in rounds 5-9.
// W2 chunk k+1 prefetched into registers during chunk k's FMA loop.
// ---------------------------------------------------------------------------
#define BP 128
#define BM 128
#define BK 64

__global__ __launch_bounds__(256, 2)
void k_h(const float* __restrict__ x, const float* __restrict__ W1,
         const float* __restrict__ b1, const float* __restrict__ W2,
         const float* __restrict__ b2, float* __restrict__ hout)
{
    __shared__ float xs[CIN_][BP];
    __shared__ __align__(16) float h1s[BK][BP + 4];
    __shared__ __align__(16) float w2s[BK][BM + 4];
    __shared__ float4 w1s[DIM_];    // .xyz = W1 row, .w = b1

    const int t  = threadIdx.x;
    const int pt = blockIdx.x, oc = blockIdx.y, b = blockIdx.z;
    const int p0 = pt * BP, o0 = oc * BM;

    w1s[t] = make_float4(W1[t * 3 + 0], W1[t * 3 + 1], W1[t * 3 + 2], b1[t]);

    for (int idx = t; idx < CIN_ * BP; idx += 256) {
        int cc = idx / BP, p = idx % BP;
        xs[cc][p] = x[((size_t)b * CIN_ + cc) * NPTS + p0 + p];
    }

    float acc[8][8];
#pragma unroll
    for (int u = 0; u < 8; ++u)
#pragma unroll
        for (int v = 0; v < 8; ++v) acc[u][v] = 0.f;

    const int pa = (t & 15) * 4;
    const int ob = ((t >> 4) & 15) * 4;

    const int cc = t & 63, r0 = t >> 6;
    float w2reg[32];
    // preload chunk 0 of W2 into registers
#pragma unroll
    for (int q = 0; q < 32; ++q)
        w2reg[q] = W2[(size_t)(o0 + r0 + q * 4) * DIM_ + cc];

    for (int kb = 0; kb < DIM_; kb += BK) {
        __syncthreads();
        // stage h1 chunk: fma chain ascending i, bias last, relu
        {
            int p  = t & 127;
            int i0 = (t >> 7) * 32;
            float x0 = xs[0][p], x1 = xs[1][p], x2 = xs[2][p];
            for (int q = 0; q < 32; ++q) {
                float4 wq = w1s[kb + i0 + q];
                float s = __fmul_rn(wq.x, x0);
                s = __builtin_fmaf(wq.y, x1, s);
                s = __builtin_fmaf(wq.z, x2, s);
                s = __fadd_rn(s, wq.w);
                h1s[i0 + q][p] = s > 0.f ? s : 0.f;
            }
        }
        // write prefetched W2 regs to LDS (transposed)
#pragma unroll
        for (int q = 0; q < 32; ++q)
            w2s[cc][r0 + q * 4] = w2reg[q];
        __syncthreads();

        // prefetch next chunk's W2 (overlaps the FMA loop below)
        if (kb + BK < DIM_) {
#pragma unroll
            for (int q = 0; q < 32; ++q)
                w2reg[q] = W2[(size_t)(o0 + r0 + q * 4) * DIM_ + kb + BK + cc];
        }

#pragma unroll 4
        for (int i = 0; i < BK; ++i) {
            float4 ha = *(const float4*)&h1s[i][pa];
            float4 hb = *(const float4*)&h1s[i][pa + 64];
            float4 wa = *(const float4*)&w2s[i][ob];
            float4 wb = *(const float4*)&w2s[i][ob + 64];
            float hv[8] = {ha.x, ha.y, ha.z, ha.w, hb.x, hb.y, hb.z, hb.w};
            float wv[8] = {wa.x, wa.y, wa.z, wa.w, wb.x, wb.y, wb.z, wb.w};
#pragma unroll
            for (int u = 0; u < 8; ++u)
#pragma unroll
                for (int v = 0; v < 8; ++v)
                    acc[u][v] = __builtin_fmaf(wv[u], hv[v], acc[u][v]);
        }
    }

#pragma unroll
    for (int u = 0; u < 8; ++u) {
        int ol = (u < 4) ? (ob + u) : (ob + 60 + u);
        int og = o0 + ol;
        float bb = b2[og];
        float4 v0 = make_float4(__fadd_rn(acc[u][0], bb), __fadd_rn(acc[u][1], bb),
                                __fadd_rn(acc[u][2], bb), __fadd_rn(acc[u][3], bb));
        float4 v1 = make_float4(__fadd_rn(acc[u][4], bb), __fadd_rn(acc[u][5], bb),
                                __fadd_rn(acc[u][6], bb), __fadd_rn(acc[u][7], bb));
        size_t rowbase = ((size_t)(b * DIM_ + og)) * NPTS + p0;
        *(float4*)&hout[rowbase + pa]      = v0;
        *(float4*)&hout[rowbase + pa + 64] = v1;
    }
}

// ---------------------------------------------------------------------------
// Kernel 2: per (b,c) row -> stable descending argsort + FSPool dot.
// Round-9 network (verified), state held as SPLIT u32 halves (rlo=idx,
// rhi=~orderable(hm)): no u64 ops anywhere -> no 64-bit shift/or
// materialization. Compare = 2-level lex on (hi, lo).
// ---------------------------------------------------------------------------
#define CE(SA, SB, ASC)                                                   \
    { u32 _alo = rlo[SA], _ahi = rhi[SA], _blo = rlo[SB], _bhi = rhi[SB]; \
      bool _gt = (_ahi > _bhi) || ((_ahi == _bhi) && (_alo > _blo));      \
      bool _sw = (_gt == (ASC));                                          \
      rlo[SA] = _sw ? _blo : _alo;  rhi[SA] = _sw ? _bhi : _ahi;          \
      rlo[SB] = _sw ? _alo : _blo;  rhi[SB] = _sw ? _ahi : _bhi; }

#define SEL(S, OLO, OHI, WANTMIN)                                         \
    { bool _lt = (rhi[S] < (OHI)) || ((rhi[S] == (OHI)) && (rlo[S] < (OLO))); \
      bool _keep = (_lt == (WANTMIN));                                    \
      rlo[S] = _keep ? rlo[S] : (OLO);  rhi[S] = _keep ? rhi[S] : (OHI); }

template<int K, int J>
__device__ __forceinline__ void cross_pass(u32 (&rlo)[16], u32 (&rhi)[16],
                                           const int t, const int lane,
                                           u32* ldsl, u32* ldsh, const bool up)
{
    if constexpr (J >= 1024) {
        const int m = J >> 4;                    // 64 or 128: cross-wave
        const bool wantmin = (((t & m) == 0) == up);
        __syncthreads();
#pragma unroll
        for (int s = 0; s < 16; ++s) { ldsl[s * 256 + t] = rlo[s]; ldsh[s * 256 + t] = rhi[s]; }
        __syncthreads();
        const int pt2 = t ^ m;
#pragma unroll
        for (int s = 0; s < 16; ++s) {
            u32 olo = ldsl[s * 256 + pt2], ohi = ldsh[s * 256 + pt2];
            SEL(s, olo, ohi, wantmin)
        }
    } else if constexpr (J == 512 || J == 256 || J == 64) {
        const int m = J >> 4;                    // 32, 16, 4: bpermute
        const bool wantmin = (((t & m) == 0) == up);
        const int ba = (lane ^ m) << 2;
#pragma unroll
        for (int s = 0; s < 16; ++s) {
            u32 olo = (u32)__builtin_amdgcn_ds_bpermute(ba, (int)rlo[s]);
            u32 ohi = (u32)__builtin_amdgcn_ds_bpermute(ba, (int)rhi[s]);
            SEL(s, olo, ohi, wantmin)
        }
    } else {
        constexpr int m    = J >> 4;             // 8, 2, 1: DPP
        constexpr int ctrl = (m == 8) ? 0x128 : (m == 2 ? 0x4E : 0xB1);
        const bool wantmin = (((t & m) == 0) == up);
#pragma unroll
        for (int s = 0; s < 16; ++s) {
            u32 olo = (u32)__builtin_amdgcn_mov_dpp((int)rlo[s], ctrl, 0xf, 0xf, true);
            u32 ohi = (u32)__builtin_amdgcn_mov_dpp((int)rhi[s], ctrl, 0xf, 0xf, true);
            SEL(s, olo, ohi, wantmin)
        }
    }
}

template<int K>
__device__ __forceinline__ void bigstage(u32 (&rlo)[16], u32 (&rhi)[16],
                                         const int t, const int lane,
                                         u32* ldsl, u32* ldsh)
{
    const bool up = ((t & (K >> 4)) == 0);
    if constexpr (K >= 4096) cross_pass<K, 2048>(rlo, rhi, t, lane, ldsl, ldsh, up);
    if constexpr (K >= 2048) cross_pass<K, 1024>(rlo, rhi, t, lane, ldsl, ldsh, up);
    if constexpr (K >= 1024) cross_pass<K, 512>(rlo, rhi, t, lane, ldsl, ldsh, up);
    if constexpr (K >= 512)  cross_pass<K, 256>(rlo, rhi, t, lane, ldsl, ldsh, up);
    if constexpr (K >= 256)  cross_pass<K, 128>(rlo, rhi, t, lane, ldsl, ldsh, up);
    if constexpr (K >= 128)  cross_pass<K, 64>(rlo, rhi, t, lane, ldsl, ldsh, up);
    if constexpr (K >= 64)   cross_pass<K, 32>(rlo, rhi, t, lane, ldsl, ldsh, up);
    cross_pass<K, 16>(rlo, rhi, t, lane, ldsl, ldsh, up);
#pragma unroll
    for (int j2 = 8; j2 >= 1; j2 >>= 1)
#pragma unroll
        for (int s = 0; s < 16; ++s)
            if ((s & j2) == 0) { CE(s, s | j2, up) }
}

__global__ __launch_bounds__(256, 2)
void k_sortpool(const float* __restrict__ hbuf, const int* __restrict__ n_points,
                const float* __restrict__ pool_w, float* __restrict__ out)
{
    __shared__ u32 ldsl[4096];
    __shared__ u32 ldsh[4096];
    __shared__ float pw[PIECES_ + 1];
    __shared__ float red[4];

    const int t    = threadIdx.x;
    const int lane = t & 63;
    const int bc   = blockIdx.x;          // b*256 + c
    const int c    = bc & 255;

    if (t < PIECES_ + 1) pw[t] = pool_w[c * (PIECES_ + 1) + t];

    const int n  = n_points[bc >> 8];
    const int dn = (n - 1) > 1 ? (n - 1) : 1;
    const float denomf = (float)dn;

    const float* hrow = hbuf + (size_t)bc * NPTS;
    u32 rlo[16], rhi[16];
#pragma unroll
    for (int s4 = 0; s4 < 4; ++s4) {
        float4 hv = *(const float4*)&hrow[t * 16 + s4 * 4];
        float hvv[4] = {hv.x, hv.y, hv.z, hv.w};
#pragma unroll
        for (int v = 0; v < 4; ++v) {
            int i = t * 16 + s4 * 4 + v;
            float hm = (i <= dn) ? hvv[v] : __fadd_rn(hvv[v], -99999.0f);
            u32 ub = __float_as_uint(hm);
            if ((ub & 0x7FFFFFFFu) == 0) ub = 0;   // canonicalize -0 -> +0
            u32 u  = (ub & 0x80000000u) ? ~ub : (ub ^ 0x80000000u);
            rhi[s4 * 4 + v] = ~u;
            rlo[s4 * 4 + v] = (u32)i;
        }
    }

    // ---- stages k = 2, 4, 8: fully compile-time ----
#pragma unroll
    for (int kk = 1; kk <= 3; ++kk) {
        const int k = 1 << kk;
#pragma unroll
        for (int j = (1 << kk) >> 1; j >= 1; j >>= 1) {
#pragma unroll
            for (int s = 0; s < 16; ++s) {
                if ((s & j) == 0) {
                    const bool asc = ((s & k) == 0);
                    CE(s, s | j, asc)
                }
            }
        }
    }

    // ---- stage k = 16: direction uniform per thread ----
    {
        const bool asc16 = ((t & 1) == 0);
#pragma unroll
        for (int j = 8; j >= 1; j >>= 1)
#pragma unroll
            for (int s = 0; s < 16; ++s)
                if ((s & j) == 0) { CE(s, s | j, asc16) }
    }

    // ---- stages k = 32..4096 ----
    bigstage<32>(rlo, rhi, t, lane, ldsl, ldsh);
    bigstage<64>(rlo, rhi, t, lane, ldsl, ldsh);
    bigstage<128>(rlo, rhi, t, lane, ldsl, ldsh);
    bigstage<256>(rlo, rhi, t, lane, ldsl, ldsh);
    bigstage<512>(rlo, rhi, t, lane, ldsl, ldsh);
    bigstage<1024>(rlo, rhi, t, lane, ldsl, ldsh);
    bigstage<2048>(rlo, rhi, t, lane, ldsl, ldsh);
    bigstage<4096>(rlo, rhi, t, lane, ldsl, ldsh);

    // ---- perm write (over the h row) + pooled partial ----
    float* permout = out + 8192 + (size_t)bc * NPTS;
    float local = 0.f;
#pragma unroll
    for (int s4 = 0; s4 < 4; ++s4) {
        float pv[4];
#pragma unroll
        for (int v = 0; v < 4; ++v) {
            int i = t * 16 + s4 * 4 + v;
            int s = s4 * 4 + v;
            pv[v] = (float)rlo[s];
            if (i <= dn) {
                u32 u    = ~rhi[s];
                u32 bits = (u & 0x80000000u) ? (u ^ 0x80000000u) : ~u;
                float hs = __uint_as_float(bits);
                float ratio = (float)i / denomf;
                float index = 20.0f * ratio;
                int   ii    = (int)index;
                if (ii > PIECES_) ii = PIECES_;
                float frac  = index - (float)ii;
                int   i2    = ii + 1 < PIECES_ ? ii + 1 : PIECES_;
                float w = (1.0f - frac) * pw[ii] + frac * pw[i2];
                local += hs * w;
            }
        }
        float4 pq = make_float4(pv[0], pv[1], pv[2], pv[3]);
        *(float4*)&permout[t * 16 + s4 * 4] = pq;
    }
#pragma unroll
    for (int off = 32; off >= 1; off >>= 1)
        local += __shfl_down(local, (unsigned)off, 64);
    if ((t & 63) == 0) red[t >> 6] = local;
    __syncthreads();
    if (t == 0) out[bc] = red[0] + red[1] + red[2] + red[3];
}

// ---------------------------------------------------------------------------
// Kernel 3: y = relu(pooled @ L1^T + bl1) @ L2^T + bl2, in place over pooled.
// ---------------------------------------------------------------------------
__global__ void k_mlp(const float* __restrict__ L1, const float* __restrict__ bl1,
                      const float* __restrict__ L2, const float* __restrict__ bl2,
                      float* __restrict__ out)
{
    __shared__ float ps[DIM_];
    __shared__ float zs[DIM_];
    const int b = blockIdx.x, t = threadIdx.x;
    ps[t] = out[b * DIM_ + t];
    __syncthreads();
    float a = bl1[t];
    for (int i = 0; i < DIM_; ++i) a += L1[t * DIM_ + i] * ps[i];
    zs[t] = a > 0.f ? a : 0.f;
    __syncthreads();
    float y = bl2[t];
    for (int i = 0; i < DIM_; ++i) y += L2[t * DIM_ + i] * zs[i];
    out[b * DIM_ + t] = y;
}

// ---------------------------------------------------------------------------
extern "C" void kernel_launch(void* const* d_in, const int* in_sizes, int n_in,
                              void* d_out, int out_size, void* d_ws, size_t ws_size,
                              hipStream_t stream)
{
    (void)in_sizes; (void)n_in; (void)d_ws; (void)ws_size; (void)out_size;

    const float* x        = (const float*)d_in[0];
    const int*   n_points = (const int*)  d_in[1];
    const float* W1       = (const float*)d_in[2];
    const float* b1       = (const float*)d_in[3];
    const float* W2       = (const float*)d_in[4];
    const float* b2       = (const float*)d_in[5];
    const float* pool_w   = (const float*)d_in[6];
    const float* L1       = (const float*)d_in[7];
    const float* bl1      = (const float*)d_in[8];
    const float* L2       = (const float*)d_in[9];
    const float* bl2      = (const float*)d_in[10];

    float* out  = (float*)d_out;
    float* hbuf = out + 8192;   // stage h in the perm region

    k_h<<<dim3(NPTS / BP, DIM_ / BM, B_), 256, 0, stream>>>(x, W1, b1, W2, b2, hbuf);
    k_sortpool<<<B_ * DIM_, 256, 0, stream>>>(hbuf, n_points, pool_w, out);
    k_mlp<<<B_, 256, 0, stream>>>(L1, bl1, L2, bl2, out);
}

// Round 11
// 490.369 us; speedup vs baseline: 1.1325x; 1.1325x over previous
//
#include <hip/hip_runtime.h>
#include <cstdint>

typedef unsigned long long u64;
typedef unsigned int u32;

#define B_      32
#define CIN_    3
#define NPTS    4096
#define DIM_    256
#define PIECES_ 20

// ---------------------------------------------------------------------------
// Kernel 1: h = W2 @ relu(W1 @ x + b1) + b2, modeling modern np.einsum
// (FMA axpy, contraction index ascending, one accumulator, bias added last).
// Verified bit-exact vs the np reference in rounds 5-10.
// W1/b1 in LDS; W2 chunk k+1 prefetched into registers during chunk k's FMAs.
// ---------------------------------------------------------------------------
#define BP 128
#define BM 128
#define BK 64

__global__ __launch_bounds__(256, 2)
void k_h(const float* __restrict__ x, const float* __restrict__ W1,
         const float* __restrict__ b1, const float* __restrict__ W2,
         const float* __restrict__ b2, float* __restrict__ hout)
{
    __shared__ float xs[CIN_][BP];
    __shared__ __align__(16) float h1s[BK][BP + 4];
    __shared__ __align__(16) float w2s[BK][BM + 4];
    __shared__ float4 w1s[DIM_];    // .xyz = W1 row, .w = b1

    const int t  = threadIdx.x;
    const int pt = blockIdx.x, oc = blockIdx.y, b = blockIdx.z;
    const int p0 = pt * BP, o0 = oc * BM;

    w1s[t] = make_float4(W1[t * 3 + 0], W1[t * 3 + 1], W1[t * 3 + 2], b1[t]);

    for (int idx = t; idx < CIN_ * BP; idx += 256) {
        int cc = idx / BP, p = idx % BP;
        xs[cc][p] = x[((size_t)b * CIN_ + cc) * NPTS + p0 + p];
    }

    float acc[8][8];
#pragma unroll
    for (int u = 0; u < 8; ++u)
#pragma unroll
        for (int v = 0; v < 8; ++v) acc[u][v] = 0.f;

    const int pa = (t & 15) * 4;
    const int ob = ((t >> 4) & 15) * 4;

    const int cc = t & 63, r0 = t >> 6;
    float w2reg[32];
#pragma unroll
    for (int q = 0; q < 32; ++q)
        w2reg[q] = W2[(size_t)(o0 + r0 + q * 4) * DIM_ + cc];

    for (int kb = 0; kb < DIM_; kb += BK) {
        __syncthreads();
        // stage h1 chunk: fma chain ascending i, bias last, relu
        {
            int p  = t & 127;
            int i0 = (t >> 7) * 32;
            float x0 = xs[0][p], x1 = xs[1][p], x2 = xs[2][p];
            for (int q = 0; q < 32; ++q) {
                float4 wq = w1s[kb + i0 + q];
                float s = __fmul_rn(wq.x, x0);
                s = __builtin_fmaf(wq.y, x1, s);
                s = __builtin_fmaf(wq.z, x2, s);
                s = __fadd_rn(s, wq.w);
                h1s[i0 + q][p] = s > 0.f ? s : 0.f;
            }
        }
        // write prefetched W2 regs to LDS (transposed)
#pragma unroll
        for (int q = 0; q < 32; ++q)
            w2s[cc][r0 + q * 4] = w2reg[q];
        __syncthreads();

        // prefetch next chunk's W2 (overlaps the FMA loop below)
        if (kb + BK < DIM_) {
#pragma unroll
            for (int q = 0; q < 32; ++q)
                w2reg[q] = W2[(size_t)(o0 + r0 + q * 4) * DIM_ + kb + BK + cc];
        }

#pragma unroll 4
        for (int i = 0; i < BK; ++i) {
            float4 ha = *(const float4*)&h1s[i][pa];
            float4 hb = *(const float4*)&h1s[i][pa + 64];
            float4 wa = *(const float4*)&w2s[i][ob];
            float4 wb = *(const float4*)&w2s[i][ob + 64];
            float hv[8] = {ha.x, ha.y, ha.z, ha.w, hb.x, hb.y, hb.z, hb.w};
            float wv[8] = {wa.x, wa.y, wa.z, wa.w, wb.x, wb.y, wb.z, wb.w};
#pragma unroll
            for (int u = 0; u < 8; ++u)
#pragma unroll
                for (int v = 0; v < 8; ++v)
                    acc[u][v] = __builtin_fmaf(wv[u], hv[v], acc[u][v]);
        }
    }

#pragma unroll
    for (int u = 0; u < 8; ++u) {
        int ol = (u < 4) ? (ob + u) : (ob + 60 + u);
        int og = o0 + ol;
        float bb = b2[og];
        float4 v0 = make_float4(__fadd_rn(acc[u][0], bb), __fadd_rn(acc[u][1], bb),
                                __fadd_rn(acc[u][2], bb), __fadd_rn(acc[u][3], bb));
        float4 v1 = make_float4(__fadd_rn(acc[u][4], bb), __fadd_rn(acc[u][5], bb),
                                __fadd_rn(acc[u][6], bb), __fadd_rn(acc[u][7], bb));
        size_t rowbase = ((size_t)(b * DIM_ + og)) * NPTS + p0;
        *(float4*)&hout[rowbase + pa]      = v0;
        *(float4*)&hout[rowbase + pa + 64] = v1;
    }
}

// ---------------------------------------------------------------------------
// Kernel 2: per (b,c) row -> stable descending argsort + FSPool dot.
// ROUND-9 VERSION (measured 304 us, VALUBusy ~95%): u64 keys, mov_dpp for
// lane^{1,2,8}, bpermute for lane^{4,16,32}, LDS for thread^{64,128}.
// NOTE (r10 lesson): split-u32 state is SLOWER (379 us) — v_cmp_lt_u64 +
// paired cndmask is the efficient codegen; do not split.
// ---------------------------------------------------------------------------
#define CE(SA, SB, ASC)                                                   \
    { u64 _a = r[SA], _b = r[SB];                                         \
      bool _sw = ((_a > _b) == (ASC));                                    \
      if (_sw) { r[SA] = _b; r[SB] = _a; } }

template<int CTRL>
__device__ __forceinline__ u64 dpp_xor(u64 v)
{
    u32 lo = (u32)v, hi = (u32)(v >> 32);
    u32 olo = (u32)__builtin_amdgcn_mov_dpp((int)lo, CTRL, 0xf, 0xf, true);
    u32 ohi = (u32)__builtin_amdgcn_mov_dpp((int)hi, CTRL, 0xf, 0xf, true);
    return ((u64)ohi << 32) | olo;
}

template<int K, int J>
__device__ __forceinline__ void cross_pass(u64 (&r)[16], const int t, const int lane,
                                           u64* lds, const bool up)
{
    if constexpr (J >= 1024) {
        const int m = J >> 4;                    // 64 or 128: cross-wave
        const bool wantmin = (((t & m) == 0) == up);
        __syncthreads();
#pragma unroll
        for (int s = 0; s < 16; ++s) lds[s * 256 + t] = r[s];
        __syncthreads();
        const int pt2 = t ^ m;
#pragma unroll
        for (int s = 0; s < 16; ++s) {
            u64 o = lds[s * 256 + pt2];
            r[s] = ((r[s] < o) == wantmin) ? r[s] : o;
        }
    } else if constexpr (J == 512 || J == 256 || J == 64) {
        const int m = J >> 4;                    // 32, 16, 4: bpermute
        const bool wantmin = (((t & m) == 0) == up);
        const int ba = (lane ^ m) << 2;
#pragma unroll
        for (int s = 0; s < 16; ++s) {
            u32 alo = (u32)r[s], ahi = (u32)(r[s] >> 32);
            u32 olo = (u32)__builtin_amdgcn_ds_bpermute(ba, (int)alo);
            u32 ohi = (u32)__builtin_amdgcn_ds_bpermute(ba, (int)ahi);
            u64 o = ((u64)ohi << 32) | olo;
            r[s] = ((r[s] < o) == wantmin) ? r[s] : o;
        }
    } else {
        constexpr int m    = J >> 4;             // 8, 2, 1: DPP
        constexpr int ctrl = (m == 8) ? 0x128 : (m == 2 ? 0x4E : 0xB1);
        const bool wantmin = (((t & m) == 0) == up);
#pragma unroll
        for (int s = 0; s < 16; ++s) {
            u64 o = dpp_xor<ctrl>(r[s]);
            r[s] = ((r[s] < o) == wantmin) ? r[s] : o;
        }
    }
}

template<int K>
__device__ __forceinline__ void bigstage(u64 (&r)[16], const int t, const int lane, u64* lds)
{
    const bool up = ((t & (K >> 4)) == 0);
    if constexpr (K >= 4096) cross_pass<K, 2048>(r, t, lane, lds, up);
    if constexpr (K >= 2048) cross_pass<K, 1024>(r, t, lane, lds, up);
    if constexpr (K >= 1024) cross_pass<K, 512>(r, t, lane, lds, up);
    if constexpr (K >= 512)  cross_pass<K, 256>(r, t, lane, lds, up);
    if constexpr (K >= 256)  cross_pass<K, 128>(r, t, lane, lds, up);
    if constexpr (K >= 128)  cross_pass<K, 64>(r, t, lane, lds, up);
    if constexpr (K >= 64)   cross_pass<K, 32>(r, t, lane, lds, up);
    cross_pass<K, 16>(r, t, lane, lds, up);
#pragma unroll
    for (int j2 = 8; j2 >= 1; j2 >>= 1)
#pragma unroll
        for (int s = 0; s < 16; ++s)
            if ((s & j2) == 0) { CE(s, s | j2, up) }
}

__global__ __launch_bounds__(256, 2)
void k_sortpool(const float* __restrict__ hbuf, const int* __restrict__ n_points,
                const float* __restrict__ pool_w, float* __restrict__ out)
{
    __shared__ u64 lds[4096];
    __shared__ float pw[PIECES_ + 1];
    __shared__ float red[4];

    const int t    = threadIdx.x;
    const int lane = t & 63;
    const int bc   = blockIdx.x;          // b*256 + c
    const int c    = bc & 255;

    if (t < PIECES_ + 1) pw[t] = pool_w[c * (PIECES_ + 1) + t];

    const int n  = n_points[bc >> 8];
    const int dn = (n - 1) > 1 ? (n - 1) : 1;
    const float denomf = (float)dn;

    const float* hrow = hbuf + (size_t)bc * NPTS;
    u64 r[16];
#pragma unroll
    for (int s4 = 0; s4 < 4; ++s4) {
        float4 hv = *(const float4*)&hrow[t * 16 + s4 * 4];
        float hvv[4] = {hv.x, hv.y, hv.z, hv.w};
#pragma unroll
        for (int v = 0; v < 4; ++v) {
            int i = t * 16 + s4 * 4 + v;
            float hm = (i <= dn) ? hvv[v] : __fadd_rn(hvv[v], -99999.0f);
            u32 ub = __float_as_uint(hm);
            if ((ub & 0x7FFFFFFFu) == 0) ub = 0;   // canonicalize -0 -> +0
            u32 u  = (ub & 0x80000000u) ? ~ub : (ub ^ 0x80000000u);
            r[s4 * 4 + v] = ((u64)(~u) << 32) | (u32)i;
        }
    }

    // ---- stages k = 2, 4, 8: fully compile-time ----
#pragma unroll
    for (int kk = 1; kk <= 3; ++kk) {
        const int k = 1 << kk;
#pragma unroll
        for (int j = (1 << kk) >> 1; j >= 1; j >>= 1) {
#pragma unroll
            for (int s = 0; s < 16; ++s) {
                if ((s & j) == 0) {
                    const bool asc = ((s & k) == 0);
                    CE(s, s | j, asc)
                }
            }
        }
    }

    // ---- stage k = 16: direction uniform per thread ----
    {
        const bool asc16 = ((t & 1) == 0);
#pragma unroll
        for (int j = 8; j >= 1; j >>= 1)
#pragma unroll
            for (int s = 0; s < 16; ++s)
                if ((s & j) == 0) { CE(s, s | j, asc16) }
    }

    // ---- stages k = 32..4096 ----
    bigstage<32>(r, t, lane, lds);
    bigstage<64>(r, t, lane, lds);
    bigstage<128>(r, t, lane, lds);
    bigstage<256>(r, t, lane, lds);
    bigstage<512>(r, t, lane, lds);
    bigstage<1024>(r, t, lane, lds);
    bigstage<2048>(r, t, lane, lds);
    bigstage<4096>(r, t, lane, lds);

    // ---- perm write (over the h row) + pooled partial ----
    float* permout = out + 8192 + (size_t)bc * NPTS;
    float local = 0.f;
#pragma unroll
    for (int s4 = 0; s4 < 4; ++s4) {
        float pv[4];
#pragma unroll
        for (int v = 0; v < 4; ++v) {
            int i = t * 16 + s4 * 4 + v;
            u64 key = r[s4 * 4 + v];
            pv[v] = (float)(u32)(key & 0xFFFFFFFFu);
            if (i <= dn) {
                u32 u    = ~(u32)(key >> 32);
                u32 bits = (u & 0x80000000u) ? (u ^ 0x80000000u) : ~u;
                float hs = __uint_as_float(bits);
                float ratio = (float)i / denomf;
                float index = 20.0f * ratio;
                int   ii    = (int)index;
                if (ii > PIECES_) ii = PIECES_;
                float frac  = index - (float)ii;
                int   i2    = ii + 1 < PIECES_ ? ii + 1 : PIECES_;
                float w = (1.0f - frac) * pw[ii] + frac * pw[i2];
                local += hs * w;
            }
        }
        float4 pq = make_float4(pv[0], pv[1], pv[2], pv[3]);
        *(float4*)&permout[t * 16 + s4 * 4] = pq;
    }
#pragma unroll
    for (int off = 32; off >= 1; off >>= 1)
        local += __shfl_down(local, (unsigned)off, 64);
    if ((t & 63) == 0) red[t >> 6] = local;
    __syncthreads();
    if (t == 0) out[bc] = red[0] + red[1] + red[2] + red[3];
}

// ---------------------------------------------------------------------------
// Kernel 3: y = relu(pooled @ L1^T + bl1) @ L2^T + bl2, in place over pooled.
// ---------------------------------------------------------------------------
__global__ void k_mlp(const float* __restrict__ L1, const float* __restrict__ bl1,
                      const float* __restrict__ L2, const float* __restrict__ bl2,
                      float* __restrict__ out)
{
    __shared__ float ps[DIM_];
    __shared__ float zs[DIM_];
    const int b = blockIdx.x, t = threadIdx.x;
    ps[t] = out[b * DIM_ + t];
    __syncthreads();
    float a = bl1[t];
    for (int i = 0; i < DIM_; ++i) a += L1[t * DIM_ + i] * ps[i];
    zs[t] = a > 0.f ? a : 0.f;
    __syncthreads();
    float y = bl2[t];
    for (int i = 0; i < DIM_; ++i) y += L2[t * DIM_ + i] * zs[i];
    out[b * DIM_ + t] = y;
}

// ---------------------------------------------------------------------------
extern "C" void kernel_launch(void* const* d_in, const int* in_sizes, int n_in,
                              void* d_out, int out_size, void* d_ws, size_t ws_size,
                              hipStream_t stream)
{
    (void)in_sizes; (void)n_in; (void)d_ws; (void)ws_size; (void)out_size;

    const float* x        = (const float*)d_in[0];
    const int*   n_points = (const int*)  d_in[1];
    const float* W1       = (const float*)d_in[2];
    const float* b1       = (const float*)d_in[3];
    const float* W2       = (const float*)d_in[4];
    const float* b2       = (const float*)d_in[5];
    const float* pool_w   = (const float*)d_in[6];
    const float* L1       = (const float*)d_in[7];
    const float* bl1      = (const float*)d_in[8];
    const float* L2       = (const float*)d_in[9];
    const float* bl2      = (const float*)d_in[10];

    float* out  = (float*)d_out;
    float* hbuf = out + 8192;   // stage h in the perm region

    k_h<<<dim3(NPTS / BP, DIM_ / BM, B_), 256, 0, stream>>>(x, W1, b1, W2, b2, hbuf);
    k_sortpool<<<B_ * DIM_, 256, 0, stream>>>(hbuf, n_points, pool_w, out);
    k_mlp<<<B_, 256, 0, stream>>>(L1, bl1, L2, bl2, out);
}